// Round 1
// baseline (428.017 us; speedup 1.0000x reference)
//
#include <hip/hip_runtime.h>
#include <hip/hip_bf16.h>

// Attention block: QKV GEMM -> 16-head softmax attention -> proj GEMM.
// B=4, T=2048, C=1024, nh=16, hs=64. All GEMMs in bf16 MFMA (16x16x32), fp32 accum.
// Reference "bug": attn out (B,nh,T,hs) flat is reinterpreted as (B*T, C) for the
// projection -> we just feed the flat [bh][t][d] buffer as proj GEMM's A matrix.

typedef __attribute__((ext_vector_type(8))) short bf16x8;   // MFMA A/B frag (4 VGPR)
typedef __attribute__((ext_vector_type(4))) float f32x4;    // MFMA C/D frag

__device__ __forceinline__ short f2bf(float f) {
    union { float f; unsigned u; } v; v.f = f;
    unsigned r = v.u + 0x7fffu + ((v.u >> 16) & 1u);   // RNE (inputs are finite)
    return (short)(r >> 16);
}

// ---------------- fp32 -> bf16 conversion ----------------
__global__ __launch_bounds__(256) void cvt_kernel(const float4* __restrict__ in,
                                                  short4* __restrict__ out, int n4) {
    int i = blockIdx.x * 256 + threadIdx.x;
    if (i < n4) {
        float4 v = in[i];
        short4 o;
        o.x = f2bf(v.x); o.y = f2bf(v.y); o.z = f2bf(v.z); o.w = f2bf(v.w);
        out[i] = o;
    }
}

// ---------------- GEMM: C[m][n] = sum_k A[m][k]*W[n][k] + bias[n] ----------------
// 128x128 tile, BK=64, 256 threads = 4 waves (2x2), each wave 64x64 out.
// EPI==0: QKV epilogue (scatter to k/q/vt, bf16, q pre-scaled by 0.125).
// EPI==1: fp32 store to outF.
template<int EPI>
__global__ __launch_bounds__(256) void gemm_bf16(
    const short* __restrict__ A, const short* __restrict__ W,
    const float* __restrict__ bias, float* __restrict__ outF,
    short* __restrict__ kout, short* __restrict__ qout, short* __restrict__ vtout,
    int M, int N, int K)
{
    __shared__ short lA[128 * 64];
    __shared__ short lB[128 * 64];
    const int tid  = threadIdx.x;
    const int lane = tid & 63;
    const int wave = tid >> 6;
    const int wM = (wave >> 1) * 64;
    const int wN = (wave & 1) * 64;
    const int l15 = lane & 15, l4 = lane >> 4;
    const int rowBase = blockIdx.y * 128;
    const int colBase = blockIdx.x * 128;

    f32x4 acc[4][4] = {};

    for (int k0 = 0; k0 < K; k0 += 64) {
        #pragma unroll
        for (int i = 0; i < 4; ++i) {
            int eo = (i * 256 + tid) * 8;     // element offset into 128x64 tile
            int r  = eo >> 6;
            int c  = eo & 63;
            *(bf16x8*)(lA + eo) = *(const bf16x8*)(A + (size_t)(rowBase + r) * K + k0 + c);
            *(bf16x8*)(lB + eo) = *(const bf16x8*)(W + (size_t)(colBase + r) * K + k0 + c);
        }
        __syncthreads();
        #pragma unroll
        for (int kt = 0; kt < 2; ++kt) {
            bf16x8 af[4], bfr[4];
            #pragma unroll
            for (int mt = 0; mt < 4; ++mt)
                af[mt] = *(const bf16x8*)(lA + (wM + mt * 16 + l15) * 64 + kt * 32 + l4 * 8);
            #pragma unroll
            for (int nt = 0; nt < 4; ++nt)
                bfr[nt] = *(const bf16x8*)(lB + (wN + nt * 16 + l15) * 64 + kt * 32 + l4 * 8);
            #pragma unroll
            for (int mt = 0; mt < 4; ++mt)
                #pragma unroll
                for (int nt = 0; nt < 4; ++nt)
                    acc[mt][nt] = __builtin_amdgcn_mfma_f32_16x16x32_bf16(
                        af[mt], bfr[nt], acc[mt][nt], 0, 0, 0);
        }
        __syncthreads();
    }

    #pragma unroll
    for (int mt = 0; mt < 4; ++mt) {
        #pragma unroll
        for (int nt = 0; nt < 4; ++nt) {
            const int n  = colBase + wN + nt * 16 + l15;
            const int mb = rowBase + wM + mt * 16 + l4 * 4;
            const float bv = bias[n];
            #pragma unroll
            for (int r = 0; r < 4; ++r) {
                const int m = mb + r;
                float val = acc[mt][nt][r] + bv;
                if (EPI == 0) {
                    // m = b*2048 + t ; n = j*1024 + h*64 + d, chunk order k,q,v
                    int b = m >> 11, t = m & 2047;
                    int j = n >> 10, hd = n & 1023;
                    int h = hd >> 6, d = hd & 63;
                    size_t base = ((size_t)(b * 16 + h) * 2048 + t) * 64 + d;
                    if (j == 0)      kout[base] = f2bf(val);
                    else if (j == 1) qout[base] = f2bf(val * 0.125f);   // fold hs^-0.5
                    else             vtout[((size_t)(b * 16 + h) * 64 + d) * 2048 + t] = f2bf(val);
                } else {
                    outF[(size_t)m * N + n] = val;
                }
            }
        }
    }
}

// ---------------- flash attention (non-causal) ----------------
// grid: (T/128, B*nh), 256 threads = 4 waves; wave owns 32 q-rows.
// Q pre-scaled by 0.125. K: [bh][t][d], Vt: [bh][d][t]. O: [bh][t][d] bf16.
__global__ __launch_bounds__(256) void attn_kernel(
    const short* __restrict__ Q, const short* __restrict__ Km,
    const short* __restrict__ Vt, short* __restrict__ O)
{
    __shared__ short plds[4][32 * 64];
    const int tid  = threadIdx.x;
    const int lane = tid & 63;
    const int wave = tid >> 6;
    const int l15 = lane & 15, l4 = lane >> 4;
    const int bh = blockIdx.y;
    const int q0 = blockIdx.x * 128 + wave * 32;

    const short* Qh = Q  + (size_t)bh * 2048 * 64;
    const short* Kh = Km + (size_t)bh * 2048 * 64;
    const short* Vh = Vt + (size_t)bh * 64 * 2048;
    short* pw = plds[wave];

    bf16x8 qf[2][2];
    #pragma unroll
    for (int rt = 0; rt < 2; ++rt)
        #pragma unroll
        for (int kt = 0; kt < 2; ++kt)
            qf[rt][kt] = *(const bf16x8*)(Qh + (size_t)(q0 + rt * 16 + l15) * 64 + kt * 32 + l4 * 8);

    f32x4 o[2][4] = {};
    float mrow[2][4], lrow[2][4];
    #pragma unroll
    for (int rt = 0; rt < 2; ++rt)
        #pragma unroll
        for (int r = 0; r < 4; ++r) { mrow[rt][r] = -1e30f; lrow[rt][r] = 0.f; }

    for (int kv = 0; kv < 2048; kv += 64) {
        f32x4 s[2][4] = {};
        #pragma unroll
        for (int kt = 0; kt < 2; ++kt) {
            bf16x8 kf[4];
            #pragma unroll
            for (int ct = 0; ct < 4; ++ct)
                kf[ct] = *(const bf16x8*)(Kh + (size_t)(kv + ct * 16 + l15) * 64 + kt * 32 + l4 * 8);
            #pragma unroll
            for (int rt = 0; rt < 2; ++rt)
                #pragma unroll
                for (int ct = 0; ct < 4; ++ct)
                    s[rt][ct] = __builtin_amdgcn_mfma_f32_16x16x32_bf16(
                        qf[rt][kt], kf[ct], s[rt][ct], 0, 0, 0);
        }
        // online softmax; row = rt*16 + l4*4 + r, col = ct*16 + l15
        #pragma unroll
        for (int rt = 0; rt < 2; ++rt) {
            #pragma unroll
            for (int r = 0; r < 4; ++r) {
                float mx = fmaxf(fmaxf(s[rt][0][r], s[rt][1][r]),
                                 fmaxf(s[rt][2][r], s[rt][3][r]));
                #pragma unroll
                for (int off = 1; off < 16; off <<= 1)
                    mx = fmaxf(mx, __shfl_xor(mx, off));
                float mnew = fmaxf(mrow[rt][r], mx);
                float corr = __expf(mrow[rt][r] - mnew);
                mrow[rt][r] = mnew;
                float ps = 0.f;
                #pragma unroll
                for (int ct = 0; ct < 4; ++ct) {
                    float p = __expf(s[rt][ct][r] - mnew);
                    s[rt][ct][r] = p;
                    ps += p;
                }
                #pragma unroll
                for (int off = 1; off < 16; off <<= 1)
                    ps += __shfl_xor(ps, off);
                lrow[rt][r] = lrow[rt][r] * corr + ps;
                #pragma unroll
                for (int dt = 0; dt < 4; ++dt)
                    o[rt][dt][r] *= corr;
            }
        }
        // P (C/D layout) -> LDS row-major [32][64] for re-fragmenting as A
        #pragma unroll
        for (int rt = 0; rt < 2; ++rt)
            #pragma unroll
            for (int ct = 0; ct < 4; ++ct)
                #pragma unroll
                for (int r = 0; r < 4; ++r)
                    pw[(rt * 16 + l4 * 4 + r) * 64 + ct * 16 + l15] = f2bf(s[rt][ct][r]);
        // PV: O += P @ V   (V from Vt, contiguous in t)
        #pragma unroll
        for (int kt = 0; kt < 2; ++kt) {
            bf16x8 pf[2], vf[4];
            #pragma unroll
            for (int rt = 0; rt < 2; ++rt)
                pf[rt] = *(const bf16x8*)(pw + (rt * 16 + l15) * 64 + kt * 32 + l4 * 8);
            #pragma unroll
            for (int dt = 0; dt < 4; ++dt)
                vf[dt] = *(const bf16x8*)(Vh + (size_t)(dt * 16 + l15) * 2048 + kv + kt * 32 + l4 * 8);
            #pragma unroll
            for (int rt = 0; rt < 2; ++rt)
                #pragma unroll
                for (int dt = 0; dt < 4; ++dt)
                    o[rt][dt] = __builtin_amdgcn_mfma_f32_16x16x32_bf16(
                        pf[rt], vf[dt], o[rt][dt], 0, 0, 0);
        }
    }
    #pragma unroll
    for (int rt = 0; rt < 2; ++rt) {
        #pragma unroll
        for (int r = 0; r < 4; ++r) {
            float inv = 1.f / lrow[rt][r];
            int qrow = q0 + rt * 16 + l4 * 4 + r;
            #pragma unroll
            for (int dt = 0; dt < 4; ++dt)
                O[((size_t)bh * 2048 + qrow) * 64 + dt * 16 + l15] =
                    f2bf(o[rt][dt][r] * inv);
        }
    }
}

// ---------------- launcher ----------------
extern "C" void kernel_launch(void* const* d_in, const int* in_sizes, int n_in,
                              void* d_out, int out_size, void* d_ws, size_t ws_size,
                              hipStream_t stream) {
    const float* x  = (const float*)d_in[0];   // (4,2048,1024)
    const float* ww = (const float*)d_in[1];   // (3072,1024)
    const float* wb = (const float*)d_in[2];   // (3072,)
    const float* pwt = (const float*)d_in[3];  // (1024,1024)
    const float* pb  = (const float*)d_in[4];  // (1024,)
    float* out = (float*)d_out;                // (4,2048,1024) fp32

    short* ws  = (short*)d_ws;
    short* xb  = ws;                      // 8192*1024
    short* wwb = xb  + 8192 * 1024;       // 3072*1024
    short* pwb = wwb + 3072 * 1024;       // 1024*1024
    short* qb  = pwb + 1024 * 1024;       // 64*2048*64  [bh][t][d] (pre-scaled)
    short* kb  = qb  + 64 * 2048 * 64;    // 64*2048*64  [bh][t][d]
    short* vtb = kb  + 64 * 2048 * 64;    // 64*64*2048  [bh][d][t]
    short* ob  = vtb + 64 * 2048 * 64;    // 64*2048*64  flat = proj A matrix

    cvt_kernel<<<2097152 / 256, 256, 0, stream>>>((const float4*)x,  (short4*)xb,  2097152);
    cvt_kernel<<< 786432 / 256, 256, 0, stream>>>((const float4*)ww, (short4*)wwb,  786432);
    cvt_kernel<<< 262144 / 256, 256, 0, stream>>>((const float4*)pwt,(short4*)pwb,  262144);

    gemm_bf16<0><<<dim3(24, 64), 256, 0, stream>>>(
        xb, wwb, wb, nullptr, kb, qb, vtb, 8192, 3072, 1024);

    attn_kernel<<<dim3(16, 64), 256, 0, stream>>>(qb, kb, vtb, ob);

    gemm_bf16<1><<<dim3(8, 64), 256, 0, stream>>>(
        ob, pwb, pb, out, nullptr, nullptr, nullptr, 8192, 1024, 1024);
}